// Round 2
// baseline (546.746 us; speedup 1.0000x reference)
//
#include <hip/hip_runtime.h>

// cumprod along dim=1 of (B=32, L=4096, C=512) fp32.
// Block owns 32 channels (8 float4) x full L=4096 chain; 8 chunks of 512 l.
// Per chunk: 8 float4/thread in regs -> local inclusive products ->
// intra-wave shfl scan over 8 l-segments (no barriers) -> one LDS exchange
// of 8 wave-totals (1 barrier/chunk, LDS double-buffered by parity) ->
// apply carry -> store. Next chunk's loads prefetched before the scan.
// Traffic = 268 MB read + 268 MB write -> ~85 us floor @ 6.3 TB/s.

constexpr int L  = 4096;
constexpr int C  = 512;
constexpr int C4 = C / 4;   // 128 float4 per row
constexpr int CG = 8;       // float4 channels per block (32 channels)
constexpr int KE = 8;       // l elements per thread per chunk
constexpr int NW = 8;       // waves per block
constexpr int SW = 8;       // l-segments per wave (w_local)
constexpr int WTH = NW * SW;       // 64 l-threads
constexpr int CL  = WTH * KE;      // 512 l per chunk
constexpr int NCHUNK = L / CL;     // 8

__device__ __forceinline__ float4 mul4(float4 a, float4 b) {
    return make_float4(a.x * b.x, a.y * b.y, a.z * b.z, a.w * b.w);
}

__device__ __forceinline__ float4 shfl_up4(float4 v, int d) {
    float4 r;
    r.x = __shfl_up(v.x, d, 64);
    r.y = __shfl_up(v.y, d, 64);
    r.z = __shfl_up(v.z, d, 64);
    r.w = __shfl_up(v.w, d, 64);
    return r;
}

__global__ __launch_bounds__(512, 4)  // cap at 128 VGPR; 2 blocks/CU
void cumprod_kernel(const float4* __restrict__ x, float4* __restrict__ out) {
    // wave totals, double-buffered by chunk parity -> only 1 barrier/chunk
    __shared__ float4 swt[2][NW][CG];

    const int tid  = threadIdx.x;
    const int c4   = tid & (CG - 1);        // fast index -> coalescing
    const int w    = tid >> 3;              // 0..63: l-segment in chunk
    const int wave = tid >> 6;              // 0..7
    const int wl   = (tid >> 3) & (SW - 1); // l-segment within wave
    const int c4g  = blockIdx.x * CG + c4;
    const int b    = blockIdx.y;
    const int base = b * L * C4 + c4g;      // float4 index of (b,0,c4g)

    float4 carry = make_float4(1.f, 1.f, 1.f, 1.f);
    float4 buf[2][KE];

    // preload chunk 0
    {
        const int lb = base + (w * KE) * C4;
#pragma unroll
        for (int i = 0; i < KE; ++i) buf[0][i] = x[lb + i * C4];
    }

#pragma unroll
    for (int chunk = 0; chunk < NCHUNK; ++chunk) {
        const int cur = chunk & 1;
        const int nxt = cur ^ 1;

        // ---- prefetch next chunk (stays in flight across the scan) ----
        if (chunk + 1 < NCHUNK) {
            const int lb = base + ((chunk + 1) * CL + w * KE) * C4;
#pragma unroll
            for (int i = 0; i < KE; ++i) buf[nxt][i] = x[lb + i * C4];
        }

        float4* v = buf[cur];

        // ---- local inclusive products (register chain) ----
#pragma unroll
        for (int i = 1; i < KE; ++i) v[i] = mul4(v[i], v[i - 1]);

        // ---- intra-wave inclusive scan over wl (lane = wl*8 + c4) ----
        float4 p = v[KE - 1];
#pragma unroll
        for (int d = 1; d < SW; d <<= 1) {
            float4 t = shfl_up4(p, d * CG);
            if (wl >= d) p = mul4(p, t);
        }
        // exclusive-within-wave prefix (from wl-1)
        float4 ew = shfl_up4(p, CG);
        if (wl == 0) ew = make_float4(1.f, 1.f, 1.f, 1.f);

        // ---- one LDS exchange of wave totals ----
        if (wl == SW - 1) swt[cur][wave][c4] = p;
        __syncthreads();

        float4 wpref = make_float4(1.f, 1.f, 1.f, 1.f);
        float4 btot  = make_float4(1.f, 1.f, 1.f, 1.f);
#pragma unroll
        for (int j = 0; j < NW; ++j) {
            float4 t = swt[cur][j][c4];
            if (j < wave) wpref = mul4(wpref, t);
            btot = mul4(btot, t);
        }

        const float4 excl = mul4(mul4(carry, wpref), ew);

        // ---- apply prefix and store ----
        const int lb = base + (chunk * CL + w * KE) * C4;
#pragma unroll
        for (int i = 0; i < KE; ++i) out[lb + i * C4] = mul4(excl, v[i]);

        carry = mul4(carry, btot);
        // no trailing barrier: next chunk writes the other LDS parity buffer
    }
}

extern "C" void kernel_launch(void* const* d_in, const int* in_sizes, int n_in,
                              void* d_out, int out_size, void* d_ws, size_t ws_size,
                              hipStream_t stream) {
    const float4* x = (const float4*)d_in[0];
    float4* out = (float4*)d_out;

    const int B = in_sizes[0] / (L * C);  // 32

    dim3 grid(C4 / CG, B);   // (16, 32) = 512 blocks
    dim3 block(512);
    cumprod_kernel<<<grid, block, 0, stream>>>(x, out);
}